// Round 4
// baseline (704.183 us; speedup 1.0000x reference)
//
#include <hip/hip_runtime.h>
#include <math.h>
#include <stddef.h>

// ---------------- problem constants ----------------
constexpr int T_ = 64;
constexpr int H_ = 1024;
constexpr int W_ = 1024;
constexpr int N_ = H_ * W_;
// int((1.0-0.15)*(N-1)) and int(0.3*(N-1)) with python double semantics
constexpr unsigned RANK_G = 891288;   // 85th pct index of gm (ascending, 0-based)
constexpr unsigned RANK_B = 314572;   // 30th pct index of |f|

constexpr int ROWS_PER_BLOCK = 32;
constexpr int BLOCKS_PER_FRAME = H_ / ROWS_PER_BLOCK; // 32

// sampling: 16 rows/frame = 16384 samples; N/NS = 64
constexpr int SROWS = 16;
constexpr int NS = SROWS * W_;              // 16384
constexpr int SHB = 8192;                   // histogram buckets (u>>18)
constexpr int MARGIN = 256;                 // sample-rank margin (~5.9 sigma in pop rank)
constexpr int RS_G = (int)(RANK_G / 64);    // 13926
constexpr int RS_B = (int)(RANK_B / 64);    // 4915

// per-block segment capacities (expected means ~2600 / ~1400 / ~220 -> 3x headroom)
constexpr unsigned CAPG = 8192;
constexpr unsigned CAPB = 4096;
constexpr unsigned CAPX = 1024;

// ---------------- workspace layout (~197 MB of 1 GiB) ----------------
struct WS {
  unsigned hist[2][T_][SHB];           // 4 MB, memset to 0 each call (must be first)
  unsigned lo[2][T_], hi[2][T_];       // value brackets (bit patterns), bucket granularity
  unsigned cntG[T_][32], cntB[T_][32], cntX[T_][32];
  unsigned cbG[T_][32], cbB[T_][32];   // per-block #{u < lo}
  float    thr[2][T_];
  double   part[T_][32][4];            // per-block certain-true partial stats
  double   accA[T_][4], accB[T_][4];   // G-resolve partials / X-resolve partials
  unsigned Gg[T_][32][CAPG];           // gm bracket candidates: gm bits
  unsigned Ga[T_][32][CAPG];           //   aux: x|y<<10|certain_bz_flag<<20
  unsigned Bb[T_][32][CAPB];           // bz bracket candidates: bz bits
  unsigned Xg[T_][32][CAPX];           // doubly-uncertain records
  unsigned Xb[T_][32][CAPX];
  unsigned Xa[T_][32][CAPX];           //   aux: x|y<<10
};

// Shared gm computation so every pass rounds identically.
__device__ __forceinline__ float gm_at(float cur, float right, float down,
                                       int col, int row) {
  float gx = (col < W_ - 1) ? (right - cur) : 0.0f;
  float gy = (row < H_ - 1) ? (down - cur) : 0.0f;
  return sqrtf(gx * gx + gy * gy);
}

// parallel exclusive prefix over partial[256] -> chunk_before[256] (wave 0 scans)
__device__ __forceinline__ void scan256(unsigned* partial, unsigned* chunk_before, int tx) {
  __syncthreads();
  if (tx < 64) {
    unsigned p0 = partial[tx * 4], p1 = partial[tx * 4 + 1];
    unsigned p2 = partial[tx * 4 + 2], p3 = partial[tx * 4 + 3];
    unsigned s = p0 + p1 + p2 + p3;
    unsigned inc = s;
    for (int d = 1; d < 64; d <<= 1) {
      unsigned y = __shfl_up(inc, d, 64);
      if (tx >= d) inc += y;
    }
    unsigned ex = inc - s;
    chunk_before[tx * 4]     = ex;
    chunk_before[tx * 4 + 1] = ex + p0;
    chunk_before[tx * 4 + 2] = ex + p0 + p1;
    chunk_before[tx * 4 + 3] = ex + p0 + p1 + p2;
  }
  __syncthreads();
}

// ---------------- pass 0a: sampled histogram (global atomics, 256 blocks) ------
__global__ __launch_bounds__(256) void sample_hist_kernel(const float* __restrict__ frames,
                                                          WS* ws) {
  const int t = blockIdx.y, qtr = blockIdx.x;
  const int tx = threadIdx.x, c = tx * 4;
  const float* f = frames + (size_t)t * N_;
  for (int r = 0; r < 4; ++r) {
    const int h = (qtr * 4 + r) * 64 + 32;          // rows 32..992, h+1 valid
    const float* row = f + (size_t)h * W_;
    float4 a = *(const float4*)(row + c);
    float an = (c + 4 < W_) ? row[c + 4] : 0.0f;
    float4 b = *(const float4*)(row + W_ + c);
    float xs[5] = {a.x, a.y, a.z, a.w, an};
    float ys[4] = {b.x, b.y, b.z, b.w};
#pragma unroll
    for (int j = 0; j < 4; ++j) {
      float gm = gm_at(xs[j], xs[j + 1], ys[j], c + j, h);
      float bz = fabsf(xs[j]);
      atomicAdd(&ws->hist[0][t][__float_as_uint(gm) >> 18], 1u);
      atomicAdd(&ws->hist[1][t][__float_as_uint(bz) >> 18], 1u);
    }
  }
}

// ---------------- pass 0b: bracket selection from histogram --------------------
__global__ __launch_bounds__(256) void bracket_kernel(WS* ws) {
  const int t = blockIdx.x, q = blockIdx.y, tx = threadIdx.x;
  __shared__ unsigned partial[256], chunk_before[256];
  const unsigned* __restrict__ h = ws->hist[q][t];
  unsigned loc[32], s = 0;
#pragma unroll
  for (int j = 0; j < 32; ++j) { loc[j] = h[tx * 32 + j]; s += loc[j]; }
  partial[tx] = s;
  scan256(partial, chunk_before, tx);
  const int rs = (q == 0) ? RS_G : RS_B;
#pragma unroll
  for (int e = 0; e < 2; ++e) {
    int k = rs + (e == 0 ? -MARGIN : MARGIN);
    if (k < 0) k = 0;
    if (k > NS - 1) k = NS - 1;
    unsigned cb = chunk_before[tx];
    if ((unsigned)k >= cb && (unsigned)k < cb + partial[tx]) {  // one thread
      unsigned rem = (unsigned)k - cb, cum = 0;
      for (int j = 0; j < 32; ++j) {
        if (rem < cum + loc[j]) {
          unsigned bucket = tx * 32 + j;
          if (e == 0) ws->lo[q][t] = bucket << 18;
          else        ws->hi[q][t] = (bucket + 1) << 18;
          break;
        }
        cum += loc[j];
      }
    }
  }
}

// ---------------- pass 1: the ONLY full streaming pass ----------------
__global__ __launch_bounds__(256) void main_kernel(const float* __restrict__ frames,
                                                   WS* ws) {
  const int t = blockIdx.y, blk = blockIdx.x, r0 = blk * ROWS_PER_BLOCK;
  const unsigned lg = ws->lo[0][t], hg = ws->hi[0][t];
  const unsigned lb = ws->lo[1][t], hb = ws->hi[1][t];
  __shared__ unsigned cnt[3];
  const int tx = threadIdx.x, c = tx * 4, lane = tx & 63, wave = tx >> 6;
  if (tx < 3) cnt[tx] = 0;
  __syncthreads();
  unsigned* __restrict__ Gg = ws->Gg[t][blk];
  unsigned* __restrict__ Ga = ws->Ga[t][blk];
  unsigned* __restrict__ Bb = ws->Bb[t][blk];
  unsigned* __restrict__ Xg = ws->Xg[t][blk];
  unsigned* __restrict__ Xb = ws->Xb[t][blk];
  unsigned* __restrict__ Xa = ws->Xa[t][blk];
  const float* f = frames + (size_t)t * N_;

  unsigned cbg = 0, cbb = 0;
  float s0 = 0.f, s1 = 0.f, s2 = 0.f, s3 = 0.f;

  for (int r = 0; r < ROWS_PER_BLOCK; ++r) {
    const int h = r0 + r;
    const float* row = f + (size_t)h * W_;
    float4 a = *(const float4*)(row + c);
    float an = (c + 4 < W_) ? row[c + 4] : 0.0f;
    float4 b;
    if (h + 1 < H_) b = *(const float4*)(row + W_ + c);
    else            b = a;                     // forces gy = 0
    float xs[5] = {a.x, a.y, a.z, a.w, an};
    float ys[4] = {b.x, b.y, b.z, b.w};
#pragma unroll
    for (int j = 0; j < 4; ++j) {
      float gm = gm_at(xs[j], xs[j + 1], ys[j], c + j, h);
      float bz = fabsf(xs[j]);
      unsigned ug = __float_as_uint(gm);
      unsigned ub = __float_as_uint(bz);
      bool bz_lo = (ub < lb);
      if (ug < lg) {
        cbg++;
      } else if (ug < hg) {                    // gm bracket candidate
        unsigned o = atomicAdd(&cnt[0], 1u);
        if (o < CAPG) {
          Gg[o] = ug;
          Ga[o] = (unsigned)(c + j) | ((unsigned)h << 10) | (bz_lo ? (1u << 20) : 0u);
        }
      }
      if (bz_lo) {
        cbb++;
        if (ug >= hg) {                        // certainly in mask
          s0 += 1.0f; s1 += gm;
          s2 += gm * (float)(c + j); s3 += gm * (float)h;
        }
      } else if (ub < hb) {                    // bz bracket candidate
        unsigned o = atomicAdd(&cnt[1], 1u);
        if (o < CAPB) Bb[o] = ub;
        if (ug >= lg) {                        // stats outcome uncertain
          unsigned o2 = atomicAdd(&cnt[2], 1u);
          if (o2 < CAPX) {
            Xg[o2] = ug; Xb[o2] = ub;
            Xa[o2] = (unsigned)(c + j) | ((unsigned)h << 10);
          }
        }
      }
    }
  }

  for (int off = 32; off; off >>= 1) {
    cbg += __shfl_down(cbg, off);
    cbb += __shfl_down(cbb, off);
    s0  += __shfl_down(s0, off);
    s1  += __shfl_down(s1, off);
    s2  += __shfl_down(s2, off);
    s3  += __shfl_down(s3, off);
  }
  __shared__ unsigned wcb[2][4];
  __shared__ float wss[4][4];
  if (lane == 0) {
    wcb[0][wave] = cbg; wcb[1][wave] = cbb;
    wss[0][wave] = s0; wss[1][wave] = s1; wss[2][wave] = s2; wss[3][wave] = s3;
  }
  __syncthreads();
  if (tx == 0) {
    ws->cbG[t][blk] = wcb[0][0] + wcb[0][1] + wcb[0][2] + wcb[0][3];
    ws->cbB[t][blk] = wcb[1][0] + wcb[1][1] + wcb[1][2] + wcb[1][3];
    ws->part[t][blk][0] = (double)wss[0][0] + wss[0][1] + wss[0][2] + wss[0][3];
    ws->part[t][blk][1] = (double)wss[1][0] + wss[1][1] + wss[1][2] + wss[1][3];
    ws->part[t][blk][2] = (double)wss[2][0] + wss[2][1] + wss[2][2] + wss[2][3];
    ws->part[t][blk][3] = (double)wss[3][0] + wss[3][1] + wss[3][2] + wss[3][3];
    unsigned c0 = cnt[0], c1 = cnt[1], c2 = cnt[2];
    ws->cntG[t][blk] = c0 < CAPG ? c0 : CAPG;
    ws->cntB[t][blk] = c1 < CAPB ? c1 : CAPB;
    ws->cntX[t][blk] = c2 < CAPX ? c2 : CAPX;
  }
}

// ---------------- pass 2: exact radix select (span-aware) + G-resolve ----------
__global__ __launch_bounds__(256) void select_kernel(WS* ws) {
  const int t = blockIdx.x, q = blockIdx.y, tx = threadIdx.x;
  const int lane = tx & 63, wave = tx >> 6;
  __shared__ unsigned hist[2048], partial[256], chunk_before[256], sel[2], nseg[32];
  __shared__ unsigned shrank;
  const unsigned lo = ws->lo[q][t], hi = ws->hi[q][t];
  const unsigned span = hi - lo;
  if (tx < 32) nseg[tx] = (q == 0) ? ws->cntG[t][tx] : ws->cntB[t][tx];
  __syncthreads();
  if (tx == 0) {
    unsigned cb = 0, total = 0;
    for (int i = 0; i < 32; ++i) {
      cb += (q == 0) ? ws->cbG[t][i] : ws->cbB[t][i];
      total += nseg[i];
    }
    long long rk = (long long)((q == 0) ? RANK_G : RANK_B) - (long long)cb;
    if (rk < 0) rk = 0;
    if (total > 0 && rk >= (long long)total) rk = (long long)total - 1;
    shrank = (unsigned)rk;
  }
  __syncthreads();
  unsigned rank = shrank, prefix = 0;
  const int startlvl = (span <= (1u << 22)) ? 1 : 0;  // skip degenerate level 0
  for (int li = startlvl; li < 3; ++li) {
    const int sh = 22 - 11 * li;                      // 22, 11, 0
    for (int i = tx; i < 2048; i += 256) hist[i] = 0;
    __syncthreads();
    for (int blk = 0; blk < 32; ++blk) {
      const unsigned n = nseg[blk];
      const unsigned* __restrict__ ptr = (q == 0) ? ws->Gg[t][blk] : ws->Bb[t][blk];
      for (unsigned i = tx; i < n; i += 256) {
        unsigned d = ptr[i] - lo;                     // candidates satisfy lo<=u<hi
        unsigned hp = (sh + 11 >= 32) ? 0u : (d >> (sh + 11));
        if (hp == prefix) atomicAdd(&hist[(d >> sh) & 2047u], 1u);
      }
    }
    __syncthreads();
    unsigned s8 = 0;
#pragma unroll
    for (int j = 0; j < 8; ++j) s8 += hist[tx * 8 + j];
    partial[tx] = s8;
    scan256(partial, chunk_before, tx);
    unsigned cb2 = chunk_before[tx];
    if (rank >= cb2 && rank < cb2 + s8) {             // exactly one thread
      unsigned rem = rank - cb2, cum = 0;
      for (int j = 0; j < 8; ++j) {
        unsigned hv = hist[tx * 8 + j];
        if (rem < cum + hv) { sel[0] = tx * 8 + j; sel[1] = rem - cum; break; }
        cum += hv;
      }
    }
    __syncthreads();
    prefix = (prefix << 11) | sel[0];
    rank = sel[1];
    __syncthreads();
  }
  const unsigned thr_bits = lo + prefix;
  if (tx == 0) ws->thr[q][t] = __uint_as_float(thr_bits);

  if (q == 0) {
    // resolve G entries (need only gm threshold + certain-bz flag)
    float c = 0.f, sg = 0.f, sx = 0.f, sy = 0.f;
    for (int blk = 0; blk < 32; ++blk) {
      const unsigned n = nseg[blk];
      const unsigned* __restrict__ Gg = ws->Gg[t][blk];
      const unsigned* __restrict__ Ga = ws->Ga[t][blk];
      for (unsigned i = tx; i < n; i += 256) {
        unsigned g = Gg[i], a = Ga[i];
        if (g > thr_bits && (a & (1u << 20))) {
          float v = __uint_as_float(g);
          c += 1.f; sg += v;
          sx += v * (float)(a & 1023u);
          sy += v * (float)((a >> 10) & 1023u);
        }
      }
    }
    for (int off = 32; off; off >>= 1) {
      c  += __shfl_down(c, off);
      sg += __shfl_down(sg, off);
      sx += __shfl_down(sx, off);
      sy += __shfl_down(sy, off);
    }
    __shared__ float pf[4][4];
    if (lane == 0) { pf[0][wave] = c; pf[1][wave] = sg; pf[2][wave] = sx; pf[3][wave] = sy; }
    __syncthreads();
    if (tx == 0) {
      ws->accA[t][0] = (double)pf[0][0] + pf[0][1] + pf[0][2] + pf[0][3];
      ws->accA[t][1] = (double)pf[1][0] + pf[1][1] + pf[1][2] + pf[1][3];
      ws->accA[t][2] = (double)pf[2][0] + pf[2][1] + pf[2][2] + pf[2][3];
      ws->accA[t][3] = (double)pf[3][0] + pf[3][1] + pf[3][2] + pf[3][3];
    }
  }
}

// ---------------- pass 3: resolve doubly-uncertain X records -------------------
__global__ __launch_bounds__(256) void resolveX_kernel(WS* ws) {
  const int t = blockIdx.x, tx = threadIdx.x;
  const int lane = tx & 63, wave = tx >> 6;
  const unsigned tg = __float_as_uint(ws->thr[0][t]);
  const unsigned tb = __float_as_uint(ws->thr[1][t]);
  float c = 0.f, sg = 0.f, sx = 0.f, sy = 0.f;
  for (int blk = 0; blk < 32; ++blk) {
    const unsigned n = ws->cntX[t][blk];
    const unsigned* __restrict__ Xg = ws->Xg[t][blk];
    const unsigned* __restrict__ Xb = ws->Xb[t][blk];
    const unsigned* __restrict__ Xa = ws->Xa[t][blk];
    for (unsigned i = tx; i < n; i += 256) {
      unsigned g = Xg[i], bb = Xb[i], a = Xa[i];
      if (g > tg && bb < tb) {
        float v = __uint_as_float(g);
        c += 1.f; sg += v;
        sx += v * (float)(a & 1023u);
        sy += v * (float)((a >> 10) & 1023u);
      }
    }
  }
  for (int off = 32; off; off >>= 1) {
    c  += __shfl_down(c, off);
    sg += __shfl_down(sg, off);
    sx += __shfl_down(sx, off);
    sy += __shfl_down(sy, off);
  }
  __shared__ float pf[4][4];
  if (lane == 0) { pf[0][wave] = c; pf[1][wave] = sg; pf[2][wave] = sx; pf[3][wave] = sy; }
  __syncthreads();
  if (tx == 0) {
    ws->accB[t][0] = (double)pf[0][0] + pf[0][1] + pf[0][2] + pf[0][3];
    ws->accB[t][1] = (double)pf[1][0] + pf[1][1] + pf[1][2] + pf[1][3];
    ws->accB[t][2] = (double)pf[2][0] + pf[2][1] + pf[2][2] + pf[2][3];
    ws->accB[t][3] = (double)pf[3][0] + pf[3][1] + pf[3][2] + pf[3][3];
  }
}

// ---------------- finalize: per-frame stats -> conv -> 8 scalars ----------------
__global__ __launch_bounds__(256) void finalize_kernel(WS* ws,
                                                       const float* __restrict__ conv_w,
                                                       const float* __restrict__ conv_b,
                                                       float* __restrict__ out) {
  __shared__ double sp[4][T_][4];
  __shared__ float st[T_][4];
  __shared__ float s[T_][4];
  const int tx = threadIdx.x;
  // stage A: parallel partial-sum of per-block stats (4 chunks of 8 blocks)
  {
    const int f = tx & 63, chunk = tx >> 6;
    double a0 = 0, a1 = 0, a2 = 0, a3 = 0;
    for (int b = chunk * 8; b < chunk * 8 + 8; ++b) {
      a0 += ws->part[f][b][0]; a1 += ws->part[f][b][1];
      a2 += ws->part[f][b][2]; a3 += ws->part[f][b][3];
    }
    sp[chunk][f][0] = a0; sp[chunk][f][1] = a1; sp[chunk][f][2] = a2; sp[chunk][f][3] = a3;
  }
  __syncthreads();
  if (tx < T_) {
    double cnt = ws->accA[tx][0] + ws->accB[tx][0];
    double sgm = ws->accA[tx][1] + ws->accB[tx][1];
    double swx = ws->accA[tx][2] + ws->accB[tx][2];
    double swy = ws->accA[tx][3] + ws->accB[tx][3];
    for (int ch = 0; ch < 4; ++ch) {
      cnt += sp[ch][tx][0]; sgm += sp[ch][tx][1];
      swx += sp[ch][tx][2]; swy += sp[ch][tx][3];
    }
    float pil  = fmaxf((float)cnt, 1e-6f);
    float wsum = fmaxf((float)sgm, 1e-6f);
    st[tx][0] = pil / (float)N_;
    st[tx][1] = (float)sgm / pil;
    st[tx][2] = (float)swx / wsum / (float)W_;
    st[tx][3] = (float)swy / wsum / (float)H_;
  }
  __syncthreads();
  if (tx < T_) {
#pragma unroll
    for (int c2 = 0; c2 < 4; ++c2) {
      float acc = conv_b[c2];
#pragma unroll
      for (int k = 0; k < 3; ++k) {
        int ti = tx + k - 1;
        if (ti >= 0 && ti < T_) acc += conv_w[c2 * 3 + k] * st[ti][c2];
      }
      s[tx][c2] = acc;
    }
  }
  __syncthreads();
  if (tx == 0) {
    float lm = 0.f, im = 0.f;
    for (int i = 0; i < T_; ++i) { lm += s[i][0]; im += s[i][1]; }
    lm /= (float)T_; im /= (float)T_;
    float lt = 0.f, it = 0.f;
    for (int i = 0; i < T_; ++i) {
      float tn = (float)i / (float)(T_ - 1) - 0.5f;
      lt += (s[i][0] - lm) * tn;
      it += (s[i][1] - im) * tn;
    }
    lt *= 6.0f / (float)T_;
    it *= 6.0f / (float)T_;
    float speeds[T_ - 1];
    float spsum = 0.f, sdx = 0.f, sdy = 0.f;
    for (int i = 0; i < T_ - 1; ++i) {
      float dx = s[i + 1][2] - s[i][2];
      float dy = s[i + 1][3] - s[i][3];
      float sp2 = sqrtf(dx * dx + dy * dy);
      speeds[i] = sp2; spsum += sp2; sdx += dx; sdy += dy;
    }
    float ms  = spsum / (float)(T_ - 1);
    float dir = atan2f(sdy, sdx) / 3.14159265358979323846f;
    float gr  = (s[T_ - 1][0] - s[0][0]) / (float)(T_ - 1);
    float var = 0.f;
    for (int i = 0; i < T_ - 1; ++i) { float d = speeds[i] - ms; var += d * d; }
    float inst = sqrtf(var / (float)(T_ - 2));
    out[0] = lm; out[1] = lt; out[2] = im; out[3] = it;
    out[4] = ms; out[5] = dir; out[6] = gr; out[7] = inst;
  }
}

// ---------------- launch ----------------
extern "C" void kernel_launch(void* const* d_in, const int* in_sizes, int n_in,
                              void* d_out, int out_size, void* d_ws, size_t ws_size,
                              hipStream_t stream) {
  const float* frames = (const float*)d_in[0];
  const float* conv_w = (const float*)d_in[2];
  const float* conv_b = (const float*)d_in[3];
  float* out = (float*)d_out;
  WS* ws = (WS*)d_ws;

  // hist is the only field that must start at zero (it's first in WS)
  hipMemsetAsync(d_ws, 0, sizeof(ws->hist), stream);

  sample_hist_kernel<<<dim3(4, T_), 256, 0, stream>>>(frames, ws);
  bracket_kernel<<<dim3(T_, 2), 256, 0, stream>>>(ws);
  main_kernel<<<dim3(BLOCKS_PER_FRAME, T_), 256, 0, stream>>>(frames, ws);
  select_kernel<<<dim3(T_, 2), 256, 0, stream>>>(ws);
  resolveX_kernel<<<T_, 256, 0, stream>>>(ws);
  finalize_kernel<<<1, 256, 0, stream>>>(ws, conv_w, conv_b, out);
}